// Round 7
// baseline (511.909 us; speedup 1.0000x reference)
//
#include <hip/hip_runtime.h>
#include <cstdint>
#include <cstddef>

// ---------------------------------------------------------------------------
// 4-layer GCN. Round 6 (resubmit; prior run died to container flake):
// single-pass plain-bf16 MFMA GEMM (W-lo dropped), gather with 16B/lane
// uint4 loads and 2 dst-rows per wave (half-wave bcast).
// ---------------------------------------------------------------------------

typedef __bf16 bf16x8 __attribute__((ext_vector_type(8)));
typedef float f32x4 __attribute__((ext_vector_type(4)));

__device__ __forceinline__ unsigned short f2bf(float v) {   // RNE
    union { float f; unsigned u; } x; x.f = v;
    unsigned r = x.u + 0x7fff + ((x.u >> 16) & 1);
    return (unsigned short)(r >> 16);
}
__device__ __forceinline__ float bf2f(unsigned short h) {
    union { unsigned u; float f; } x; x.u = (unsigned)h << 16; return x.f;
}

// async global->LDS, 16B per lane; lds base must be wave-uniform
__device__ __forceinline__ void gl2lds16(const void* g, void* l) {
    __builtin_amdgcn_global_load_lds(
        (const __attribute__((address_space(1))) unsigned int*)g,
        (__attribute__((address_space(3))) unsigned int*)l, 16, 0, 0);
}

// acc[0..7] += bf16x8(v) * n
__device__ __forceinline__ void fma8(const uint4 v, float n, float* acc) {
    acc[0] += bf2f((unsigned short)(v.x & 0xffff)) * n;
    acc[1] += bf2f((unsigned short)(v.x >> 16)) * n;
    acc[2] += bf2f((unsigned short)(v.y & 0xffff)) * n;
    acc[3] += bf2f((unsigned short)(v.y >> 16)) * n;
    acc[4] += bf2f((unsigned short)(v.z & 0xffff)) * n;
    acc[5] += bf2f((unsigned short)(v.z >> 16)) * n;
    acc[6] += bf2f((unsigned short)(v.w & 0xffff)) * n;
    acc[7] += bf2f((unsigned short)(v.w >> 16)) * n;
}

// ---------------- edge-index dtype detection -------------------------------
__global__ void k_flag_init(int* flag) {
    if (blockIdx.x == 0 && threadIdx.x == 0) *flag = 1;
}

__global__ void k_flag_check(const long long* __restrict__ p, int E, long long N,
                             int* flag) {
    long long i = (long long)blockIdx.x * blockDim.x + threadIdx.x;
    long long stride = (long long)gridDim.x * blockDim.x;
    for (; i < E; i += stride) {
        long long v = p[i];
        if (v < 0 || v >= N) *flag = 0;
    }
}

__device__ __forceinline__ void load_edge(const void* eidx, int fl, int E, int i,
                                          int& s, int& d) {
    if (fl) {
        s = (int)((const long long*)eidx)[i];
        d = (int)((const long long*)eidx)[E + i];
    } else {
        s = ((const int*)eidx)[i];
        d = ((const int*)eidx)[E + i];
    }
}

// ---------------- CSR build -------------------------------------------------
__global__ void k_zero_i32(int* __restrict__ p, int n) {
    int i = blockIdx.x * blockDim.x + threadIdx.x;
    if (i < n) p[i] = 0;
}

__global__ void k_count(const void* __restrict__ eidx, const int* __restrict__ flag,
                        int* __restrict__ counts, int E) {
    int i = blockIdx.x * blockDim.x + threadIdx.x;
    if (i >= E) return;
    int s, d;
    load_edge(eidx, *flag, E, i, s, d);
    atomicAdd(&counts[d], 1);
}

__global__ void k_dinv(const int* __restrict__ counts, float* __restrict__ dinv,
                       int N) {
    int i = blockIdx.x * blockDim.x + threadIdx.x;
    if (i < N) dinv[i] = rsqrtf((float)counts[i] + 1.0f);
}

__global__ __launch_bounds__(1024) void k_scan(const int* __restrict__ counts,
                                               int* __restrict__ starts, int N) {
    __shared__ int wsum[16];
    __shared__ int wscan[16];
    __shared__ int s_carry;
    int tid = threadIdx.x;
    int lane = tid & 63, wid = tid >> 6;
    if (tid == 0) s_carry = 0;
    __syncthreads();
    for (int base = 0; base < N; base += 1024) {
        int i = base + tid;
        int v = (i < N) ? counts[i] : 0;
        int incl = v;
#pragma unroll
        for (int off = 1; off < 64; off <<= 1) {
            int t = __shfl_up(incl, off);
            if (lane >= off) incl += t;
        }
        if (lane == 63) wsum[wid] = incl;
        __syncthreads();
        if (wid == 0 && lane < 16) {
            int w = wsum[lane];
#pragma unroll
            for (int off = 1; off < 16; off <<= 1) {
                int t = __shfl_up(w, off);
                if (lane >= off) w += t;
            }
            wscan[lane] = w;
        }
        __syncthreads();
        int woff = (wid > 0) ? wscan[wid - 1] : 0;
        int excl = s_carry + woff + incl - v;
        if (i < N) starts[i] = excl;
        int total = wscan[15];
        __syncthreads();
        if (tid == 0) s_carry += total;
        __syncthreads();
    }
    if (tid == 0) starts[N] = s_carry;
}

__global__ void k_copy_i32(const int* __restrict__ a, int* __restrict__ b, int n) {
    int i = blockIdx.x * blockDim.x + threadIdx.x;
    if (i < n) b[i] = a[i];
}

__global__ void k_fill(const void* __restrict__ eidx, const int* __restrict__ flag,
                       int* __restrict__ cursor, int* __restrict__ srcs, int E) {
    int i = blockIdx.x * blockDim.x + threadIdx.x;
    if (i >= E) return;
    int s, d;
    load_edge(eidx, *flag, E, i, s, d);
    int pos = atomicAdd(&cursor[d], 1);
    srcs[pos] = s;
}

// ---------------- conversions ----------------------------------------------
__global__ void k_cvt_x(const float* __restrict__ x, unsigned short* __restrict__ o,
                        long long n4) {
    long long i = (long long)blockIdx.x * blockDim.x + threadIdx.x;
    long long stride = (long long)gridDim.x * blockDim.x;
    for (; i < n4; i += stride) {
        float4 v = ((const float4*)x)[i];
        unsigned a = (unsigned)f2bf(v.x) | ((unsigned)f2bf(v.y) << 16);
        unsigned b = (unsigned)f2bf(v.z) | ((unsigned)f2bf(v.w) << 16);
        ((uint2*)o)[i] = make_uint2(a, b);
    }
}

// W [K][H] fp32 -> transposed, padded [256][256] plain bf16 (zeros outside)
__global__ void k_cvt_w(const float* __restrict__ W, unsigned short* __restrict__ T,
                        int K, int H) {
    int idx = blockIdx.x * blockDim.x + threadIdx.x;
    if (idx >= 256 * 256) return;
    int k = idx & 255, n = idx >> 8;
    float v = (k < K && n < H) ? W[k * H + n] : 0.0f;
    T[n * 256 + k] = f2bf(v);
}

// ---------------- single-pass bf16 MFMA GEMM -------------------------------
// C[M][256] = A[M][256] @ W[256][256]; A plain bf16, W transposed bf16.
// 128x128 tile, 4 waves, 4x4 grid of 16x16x32 MFMA.
// Staging via global_load_lds (16B/lane, wave-uniform LDS base).
__global__ __launch_bounds__(256) void k_gemm_mfma(
        const unsigned short* __restrict__ A,
        const unsigned short* __restrict__ BT,
        unsigned short* __restrict__ C, int M) {
    __shared__ unsigned short ldsA[4 * 128 * 8];    // chunk c = kq*128+m
    __shared__ unsigned short ldsB[4 * 128 * 8];    // chunk c = kq*128+n

    int tid = threadIdx.x;
    int lane = tid & 63;
    int w = tid >> 6;
    int wm = (w & 1) * 64, wn = (w >> 1) * 64;
    int kq = lane >> 4, lr = lane & 15;
    int row0 = blockIdx.y * 128, col0 = blockIdx.x * 128;

    f32x4 acc[4][4] = {};

    for (int k0 = 0; k0 < 256; k0 += 32) {
        __syncthreads();
#pragma unroll
        for (int i = 0; i < 2; i++) {
            int c = (i * 4 + w) * 64 + lane;
            int m = c & 127, kqq = c >> 7;
            int row = row0 + m; if (row >= M) row = M - 1;   // clamp: valid addr
            gl2lds16(&A[(long long)row * 256 + k0 + kqq * 8],
                     &ldsA[(i * 4 + w) * 512]);
        }
#pragma unroll
        for (int i = 0; i < 2; i++) {
            int c = (i * 4 + w) * 64 + lane;
            int n = c & 127, kqq = c >> 7;
            gl2lds16(&BT[(long long)(col0 + n) * 256 + k0 + kqq * 8],
                     &ldsB[(i * 4 + w) * 512]);
        }
        __syncthreads();

        bf16x8 a[4], b[4];
#pragma unroll
        for (int t = 0; t < 4; t++) {
            int m = wm + t * 16 + lr;
            a[t] = *(const bf16x8*)&ldsA[(kq * 128 + m) * 8];
            int n = wn + t * 16 + lr;
            b[t] = *(const bf16x8*)&ldsB[(kq * 128 + n) * 8];
        }
#pragma unroll
        for (int mt = 0; mt < 4; mt++)
#pragma unroll
            for (int nt = 0; nt < 4; nt++)
                acc[mt][nt] = __builtin_amdgcn_mfma_f32_16x16x32_bf16(
                    a[mt], b[nt], acc[mt][nt], 0, 0, 0);
    }

    // epilogue: C/D layout col=lane&15, row=(lane>>4)*4+reg  [m89-verified]
#pragma unroll
    for (int mt = 0; mt < 4; mt++) {
#pragma unroll
        for (int nt = 0; nt < 4; nt++) {
            int col = col0 + wn + nt * 16 + lr;
            int rowb = row0 + wm + mt * 16 + kq * 4;
#pragma unroll
            for (int r = 0; r < 4; r++) {
                int row = rowb + r;
                if (row < M) C[(long long)row * 256 + col] = f2bf(acc[mt][nt][r]);
            }
        }
    }
}

// ---------------- wave-per-2-dst CSR gather (bf16 in, bf16 out) ------------
// Each wave: lanes 0-31 handle dst d0, lanes 32-63 handle d0+1.
// Each lane covers 8 features (16B uint4).
// out = relu( dinv[d]*( h[d]*dinv[d] + sum_s h[s]*dinv[s] ) + bias )
__global__ __launch_bounds__(256) void k_gather_bf16(
        const unsigned short* __restrict__ h,   // bf16 [N][256]
        const int* __restrict__ srcs, const int* __restrict__ starts,
        const float* __restrict__ dinv, const float* __restrict__ bias,
        unsigned short* __restrict__ out, int N, int H) {
    int wid = threadIdx.x >> 6;
    int lane = threadIdx.x & 63;
    int half = lane >> 5, hl = lane & 31;
    int d = blockIdx.x * 8 + wid * 2 + half;
    if (d >= N) return;
    int f0 = hl * 8;
    float dd = dinv[d];
    int e0 = starts[d], e1 = starts[d + 1];
    int cnt = e1 - e0;
    int cpre = cnt < 32 ? cnt : 32;

    float acc[8];
    {   // self-loop
        uint4 v = *(const uint4*)&h[((long long)d << 8) + f0];
        for (int t = 0; t < 8; t++) acc[t] = 0.0f;
        fma8(v, dd, acc);
    }
    int sv = 0; float nv = 0.0f;
    if (hl < cpre) { sv = srcs[e0 + hl]; nv = dinv[sv]; }
    int hb = half << 5;
    int j = 0;
    for (; j + 1 < cpre; j += 2) {
        int s0 = __shfl(sv, hb + j), s1 = __shfl(sv, hb + j + 1);
        float n0 = __shfl(nv, hb + j), n1 = __shfl(nv, hb + j + 1);
        uint4 v0 = *(const uint4*)&h[((long long)s0 << 8) + f0];
        uint4 v1 = *(const uint4*)&h[((long long)s1 << 8) + f0];
        fma8(v0, n0, acc);
        fma8(v1, n1, acc);
    }
    if (j < cpre) {
        int s0 = __shfl(sv, hb + j);
        float n0 = __shfl(nv, hb + j);
        uint4 v0 = *(const uint4*)&h[((long long)s0 << 8) + f0];
        fma8(v0, n0, acc);
    }
    for (int e = e0 + 32; e < e1; e++) {          // rare: degree > 32
        int s0 = srcs[e];
        float n0 = dinv[s0];
        uint4 v0 = *(const uint4*)&h[((long long)s0 << 8) + f0];
        fma8(v0, n0, acc);
    }

    unsigned short o[8];
#pragma unroll
    for (int t = 0; t < 8; t++) {
        int f = f0 + t;
        float bb = (f < H) ? bias[f] : 0.0f;
        float v = fmaxf(acc[t] * dd + bb, 0.0f);   // relu; pad cols stay 0
        o[t] = f2bf(v);
    }
    uint4 ov;
    ov.x = (unsigned)o[0] | ((unsigned)o[1] << 16);
    ov.y = (unsigned)o[2] | ((unsigned)o[3] << 16);
    ov.z = (unsigned)o[4] | ((unsigned)o[5] << 16);
    ov.w = (unsigned)o[6] | ((unsigned)o[7] << 16);
    *(uint4*)&out[((long long)d << 8) + f0] = ov;
}

// ---------------- layer-4: gather + fused log_softmax (2 dst/wave) ---------
__global__ __launch_bounds__(256) void k_gather_lsm(
        const unsigned short* __restrict__ h,   // bf16 [N][256]
        const int* __restrict__ srcs, const int* __restrict__ starts,
        const float* __restrict__ dinv, const float* __restrict__ bias,
        float* __restrict__ out, int N, int H) {
    int wid = threadIdx.x >> 6;
    int lane = threadIdx.x & 63;
    int half = lane >> 5, hl = lane & 31;
    int d = blockIdx.x * 8 + wid * 2 + half;
    if (d >= N) return;
    int f0 = hl * 8;
    float dd = dinv[d];
    int e0 = starts[d], e1 = starts[d + 1];
    int cnt = e1 - e0;
    int cpre = cnt < 32 ? cnt : 32;

    float acc[8];
    {
        uint4 v = *(const uint4*)&h[((long long)d << 8) + f0];
        for (int t = 0; t < 8; t++) acc[t] = 0.0f;
        fma8(v, dd, acc);
    }
    int sv = 0; float nv = 0.0f;
    if (hl < cpre) { sv = srcs[e0 + hl]; nv = dinv[sv]; }
    int hb = half << 5;
    int j = 0;
    for (; j + 1 < cpre; j += 2) {
        int s0 = __shfl(sv, hb + j), s1 = __shfl(sv, hb + j + 1);
        float n0 = __shfl(nv, hb + j), n1 = __shfl(nv, hb + j + 1);
        uint4 v0 = *(const uint4*)&h[((long long)s0 << 8) + f0];
        uint4 v1 = *(const uint4*)&h[((long long)s1 << 8) + f0];
        fma8(v0, n0, acc);
        fma8(v1, n1, acc);
    }
    if (j < cpre) {
        int s0 = __shfl(sv, hb + j);
        float n0 = __shfl(nv, hb + j);
        uint4 v0 = *(const uint4*)&h[((long long)s0 << 8) + f0];
        fma8(v0, n0, acc);
    }
    for (int e = e0 + 32; e < e1; e++) {
        int s0 = srcs[e];
        float n0 = dinv[s0];
        uint4 v0 = *(const uint4*)&h[((long long)s0 << 8) + f0];
        fma8(v0, n0, acc);
    }

    float v[8];
    float m = -INFINITY;
#pragma unroll
    for (int t = 0; t < 8; t++) {
        int f = f0 + t;
        float bb = (f < H) ? bias[f] : 0.0f;
        v[t] = acc[t] * dd + bb;
        if (f < H) m = fmaxf(m, v[t]);
    }
    // half-wave (32-lane) reduction: xor offsets stay inside the half
#pragma unroll
    for (int off = 16; off > 0; off >>= 1) m = fmaxf(m, __shfl_xor(m, off));
    float s = 0.0f;
#pragma unroll
    for (int t = 0; t < 8; t++) {
        int f = f0 + t;
        if (f < H) s += __expf(v[t] - m);
    }
#pragma unroll
    for (int off = 16; off > 0; off >>= 1) s += __shfl_xor(s, off);
    float lse = m + logf(s);
#pragma unroll
    for (int t = 0; t < 8; t++) {
        int f = f0 + t;
        if (f < H) out[(long long)d * H + f] = v[t] - lse;
    }
}

// ---------------------------------------------------------------------------
extern "C" void kernel_launch(void* const* d_in, const int* in_sizes, int n_in,
                              void* d_out, int out_size, void* d_ws, size_t ws_size,
                              hipStream_t stream) {
    const float* x    = (const float*)d_in[0];
    const void*  eidx = d_in[1];
    const float* W[4] = {(const float*)d_in[2], (const float*)d_in[4],
                         (const float*)d_in[6], (const float*)d_in[8]};
    const float* b[4] = {(const float*)d_in[3], (const float*)d_in[5],
                         (const float*)d_in[7], (const float*)d_in[9]};

    const int H   = in_sizes[3];          // 246
    const int E   = in_sizes[1] / 2;      // 320000
    const int FIN = in_sizes[2] / H;      // 256
    const int N   = in_sizes[0] / FIN;    // 50000

    auto align = [](size_t v) { return (v + 255) / 256 * 256; };
    char* ws = (char*)d_ws;
    size_t off = 0;
    int* flag = (int*)(ws + off);             off += 256;
    float* dinv = (float*)(ws + off);         off += align((size_t)N * 4);
    int* counts = (int*)(ws + off);           off += align((size_t)N * 4);
    int* starts = (int*)(ws + off);           off += align((size_t)(N + 1) * 4);
    int* srcs = (int*)(ws + off);             off += align((size_t)E * 4);
    unsigned short* Wt[4];
    for (int l = 0; l < 4; l++) {
        Wt[l] = (unsigned short*)(ws + off);  off += 256 * 256 * 2;
    }
    size_t actB = align((size_t)N * 256 * 2);
    unsigned short* A0 = (unsigned short*)(ws + off);  off += actB;
    unsigned short* A1 = (unsigned short*)(ws + off);  off += actB;
    unsigned short* Cb = (unsigned short*)(ws + off);  off += actB;

    int nb = (N + 255) / 256, eb = (E + 255) / 256;

    // --- edge dtype detection ---
    k_flag_init<<<1, 64, 0, stream>>>(flag);
    k_flag_check<<<512, 256, 0, stream>>>((const long long*)eidx, E, (long long)N, flag);

    // --- CSR build ---
    k_zero_i32<<<nb, 256, 0, stream>>>(counts, N);
    k_count<<<eb, 256, 0, stream>>>(eidx, flag, counts, E);
    k_dinv<<<nb, 256, 0, stream>>>(counts, dinv, N);
    k_scan<<<1, 1024, 0, stream>>>(counts, starts, N);
    k_copy_i32<<<nb, 256, 0, stream>>>(starts, counts, N);
    k_fill<<<eb, 256, 0, stream>>>(eidx, flag, counts, srcs, E);

    // --- weight + input conversion ---
    k_cvt_w<<<256, 256, 0, stream>>>(W[0], Wt[0], FIN, H);
    for (int l = 1; l < 4; l++)
        k_cvt_w<<<256, 256, 0, stream>>>(W[l], Wt[l], H, H);
    k_cvt_x<<<1024, 256, 0, stream>>>(x, A0, (long long)N * FIN / 4);

    dim3 ggrid(2, (N + 127) / 128);
    int gb = (N + 7) / 8;

    // --- layer 1 ---
    k_gemm_mfma<<<ggrid, 256, 0, stream>>>(A0, Wt[0], Cb, N);
    k_gather_bf16<<<gb, 256, 0, stream>>>(Cb, srcs, starts, dinv, b[0], A1, N, H);
    // --- layer 2 ---
    k_gemm_mfma<<<ggrid, 256, 0, stream>>>(A1, Wt[1], Cb, N);
    k_gather_bf16<<<gb, 256, 0, stream>>>(Cb, srcs, starts, dinv, b[1], A0, N, H);
    // --- layer 3 ---
    k_gemm_mfma<<<ggrid, 256, 0, stream>>>(A0, Wt[2], Cb, N);
    k_gather_bf16<<<gb, 256, 0, stream>>>(Cb, srcs, starts, dinv, b[2], A1, N, H);
    // --- layer 4 (fused log_softmax) ---
    k_gemm_mfma<<<ggrid, 256, 0, stream>>>(A1, Wt[3], Cb, N);
    k_gather_lsm<<<gb, 256, 0, stream>>>(Cb, srcs, starts, dinv, b[3],
                                         (float*)d_out, N, H);
}

// Round 10
// 471.469 us; speedup vs baseline: 1.0858x; 1.0858x over previous
//
#include <hip/hip_runtime.h>
#include <cstdint>
#include <cstddef>

// ---------------------------------------------------------------------------
// 4-layer GCN. Round 10: composed strictly from HW-passing fragments.
// Gather = round-5 shape (64-lane/1-dst, uint2/lane, 2-deep unroll, full-wave
// shfl bcast) with round-7's single-bf16 epilogue. GEMM/CSR/conversions =
// round-7 verbatim (single-pass bf16 MFMA; W-lo drop cost zero absmax).
// ---------------------------------------------------------------------------

typedef __bf16 bf16x8 __attribute__((ext_vector_type(8)));
typedef float f32x4 __attribute__((ext_vector_type(4)));

__device__ __forceinline__ unsigned short f2bf(float v) {   // RNE
    union { float f; unsigned u; } x; x.f = v;
    unsigned r = x.u + 0x7fff + ((x.u >> 16) & 1);
    return (unsigned short)(r >> 16);
}
__device__ __forceinline__ float bf2f(unsigned short h) {
    union { unsigned u; float f; } x; x.u = (unsigned)h << 16; return x.f;
}

// async global->LDS, 16B per lane; lds base must be wave-uniform
__device__ __forceinline__ void gl2lds16(const void* g, void* l) {
    __builtin_amdgcn_global_load_lds(
        (const __attribute__((address_space(1))) unsigned int*)g,
        (__attribute__((address_space(3))) unsigned int*)l, 16, 0, 0);
}

// acc[0..3] += bf16x4(v) * n
__device__ __forceinline__ void fma4(const uint2 v, float n, float* acc) {
    acc[0] += bf2f((unsigned short)(v.x & 0xffff)) * n;
    acc[1] += bf2f((unsigned short)(v.x >> 16)) * n;
    acc[2] += bf2f((unsigned short)(v.y & 0xffff)) * n;
    acc[3] += bf2f((unsigned short)(v.y >> 16)) * n;
}

// ---------------- edge-index dtype detection -------------------------------
__global__ void k_flag_init(int* flag) {
    if (blockIdx.x == 0 && threadIdx.x == 0) *flag = 1;
}

__global__ void k_flag_check(const long long* __restrict__ p, int E, long long N,
                             int* flag) {
    long long i = (long long)blockIdx.x * blockDim.x + threadIdx.x;
    long long stride = (long long)gridDim.x * blockDim.x;
    for (; i < E; i += stride) {
        long long v = p[i];
        if (v < 0 || v >= N) *flag = 0;
    }
}

__device__ __forceinline__ void load_edge(const void* eidx, int fl, int E, int i,
                                          int& s, int& d) {
    if (fl) {
        s = (int)((const long long*)eidx)[i];
        d = (int)((const long long*)eidx)[E + i];
    } else {
        s = ((const int*)eidx)[i];
        d = ((const int*)eidx)[E + i];
    }
}

// ---------------- CSR build -------------------------------------------------
__global__ void k_zero_i32(int* __restrict__ p, int n) {
    int i = blockIdx.x * blockDim.x + threadIdx.x;
    if (i < n) p[i] = 0;
}

__global__ void k_count(const void* __restrict__ eidx, const int* __restrict__ flag,
                        int* __restrict__ counts, int E) {
    int i = blockIdx.x * blockDim.x + threadIdx.x;
    if (i >= E) return;
    int s, d;
    load_edge(eidx, *flag, E, i, s, d);
    atomicAdd(&counts[d], 1);
}

__global__ void k_dinv(const int* __restrict__ counts, float* __restrict__ dinv,
                       int N) {
    int i = blockIdx.x * blockDim.x + threadIdx.x;
    if (i < N) dinv[i] = rsqrtf((float)counts[i] + 1.0f);
}

__global__ __launch_bounds__(1024) void k_scan(const int* __restrict__ counts,
                                               int* __restrict__ starts, int N) {
    __shared__ int wsum[16];
    __shared__ int wscan[16];
    __shared__ int s_carry;
    int tid = threadIdx.x;
    int lane = tid & 63, wid = tid >> 6;
    if (tid == 0) s_carry = 0;
    __syncthreads();
    for (int base = 0; base < N; base += 1024) {
        int i = base + tid;
        int v = (i < N) ? counts[i] : 0;
        int incl = v;
#pragma unroll
        for (int off = 1; off < 64; off <<= 1) {
            int t = __shfl_up(incl, off);
            if (lane >= off) incl += t;
        }
        if (lane == 63) wsum[wid] = incl;
        __syncthreads();
        if (wid == 0 && lane < 16) {
            int w = wsum[lane];
#pragma unroll
            for (int off = 1; off < 16; off <<= 1) {
                int t = __shfl_up(w, off);
                if (lane >= off) w += t;
            }
            wscan[lane] = w;
        }
        __syncthreads();
        int woff = (wid > 0) ? wscan[wid - 1] : 0;
        int excl = s_carry + woff + incl - v;
        if (i < N) starts[i] = excl;
        int total = wscan[15];
        __syncthreads();
        if (tid == 0) s_carry += total;
        __syncthreads();
    }
    if (tid == 0) starts[N] = s_carry;
}

__global__ void k_copy_i32(const int* __restrict__ a, int* __restrict__ b, int n) {
    int i = blockIdx.x * blockDim.x + threadIdx.x;
    if (i < n) b[i] = a[i];
}

__global__ void k_fill(const void* __restrict__ eidx, const int* __restrict__ flag,
                       int* __restrict__ cursor, int* __restrict__ srcs, int E) {
    int i = blockIdx.x * blockDim.x + threadIdx.x;
    if (i >= E) return;
    int s, d;
    load_edge(eidx, *flag, E, i, s, d);
    int pos = atomicAdd(&cursor[d], 1);
    srcs[pos] = s;
}

// ---------------- conversions ----------------------------------------------
__global__ void k_cvt_x(const float* __restrict__ x, unsigned short* __restrict__ o,
                        long long n4) {
    long long i = (long long)blockIdx.x * blockDim.x + threadIdx.x;
    long long stride = (long long)gridDim.x * blockDim.x;
    for (; i < n4; i += stride) {
        float4 v = ((const float4*)x)[i];
        unsigned a = (unsigned)f2bf(v.x) | ((unsigned)f2bf(v.y) << 16);
        unsigned b = (unsigned)f2bf(v.z) | ((unsigned)f2bf(v.w) << 16);
        ((uint2*)o)[i] = make_uint2(a, b);
    }
}

// W [K][H] fp32 -> transposed, padded [256][256] plain bf16 (zeros outside)
__global__ void k_cvt_w(const float* __restrict__ W, unsigned short* __restrict__ T,
                        int K, int H) {
    int idx = blockIdx.x * blockDim.x + threadIdx.x;
    if (idx >= 256 * 256) return;
    int k = idx & 255, n = idx >> 8;
    float v = (k < K && n < H) ? W[k * H + n] : 0.0f;
    T[n * 256 + k] = f2bf(v);
}

// ---------------- single-pass bf16 MFMA GEMM -------------------------------
// C[M][256] = A[M][256] @ W[256][256]; A plain bf16, W transposed bf16.
// 128x128 tile, 4 waves, 4x4 grid of 16x16x32 MFMA.
// Staging via global_load_lds (16B/lane, wave-uniform LDS base).
__global__ __launch_bounds__(256) void k_gemm_mfma(
        const unsigned short* __restrict__ A,
        const unsigned short* __restrict__ BT,
        unsigned short* __restrict__ C, int M) {
    __shared__ unsigned short ldsA[4 * 128 * 8];    // chunk c = kq*128+m
    __shared__ unsigned short ldsB[4 * 128 * 8];    // chunk c = kq*128+n

    int tid = threadIdx.x;
    int lane = tid & 63;
    int w = tid >> 6;
    int wm = (w & 1) * 64, wn = (w >> 1) * 64;
    int kq = lane >> 4, lr = lane & 15;
    int row0 = blockIdx.y * 128, col0 = blockIdx.x * 128;

    f32x4 acc[4][4] = {};

    for (int k0 = 0; k0 < 256; k0 += 32) {
        __syncthreads();
#pragma unroll
        for (int i = 0; i < 2; i++) {
            int c = (i * 4 + w) * 64 + lane;
            int m = c & 127, kqq = c >> 7;
            int row = row0 + m; if (row >= M) row = M - 1;   // clamp: valid addr
            gl2lds16(&A[(long long)row * 256 + k0 + kqq * 8],
                     &ldsA[(i * 4 + w) * 512]);
        }
#pragma unroll
        for (int i = 0; i < 2; i++) {
            int c = (i * 4 + w) * 64 + lane;
            int n = c & 127, kqq = c >> 7;
            gl2lds16(&BT[(long long)(col0 + n) * 256 + k0 + kqq * 8],
                     &ldsB[(i * 4 + w) * 512]);
        }
        __syncthreads();

        bf16x8 a[4], b[4];
#pragma unroll
        for (int t = 0; t < 4; t++) {
            int m = wm + t * 16 + lr;
            a[t] = *(const bf16x8*)&ldsA[(kq * 128 + m) * 8];
            int n = wn + t * 16 + lr;
            b[t] = *(const bf16x8*)&ldsB[(kq * 128 + n) * 8];
        }
#pragma unroll
        for (int mt = 0; mt < 4; mt++)
#pragma unroll
            for (int nt = 0; nt < 4; nt++)
                acc[mt][nt] = __builtin_amdgcn_mfma_f32_16x16x32_bf16(
                    a[mt], b[nt], acc[mt][nt], 0, 0, 0);
    }

    // epilogue: C/D layout col=lane&15, row=(lane>>4)*4+reg  [m89-verified]
#pragma unroll
    for (int mt = 0; mt < 4; mt++) {
#pragma unroll
        for (int nt = 0; nt < 4; nt++) {
            int col = col0 + wn + nt * 16 + lr;
            int rowb = row0 + wm + mt * 16 + kq * 4;
#pragma unroll
            for (int r = 0; r < 4; r++) {
                int row = rowb + r;
                if (row < M) C[(long long)row * 256 + col] = f2bf(acc[mt][nt][r]);
            }
        }
    }
}

// ---------------- wave-per-dst CSR gather (bf16 in, bf16 out) --------------
// 64 lanes = 1 dst row; 4 features/lane (uint2); 2-deep edge unroll
// (round-5-proven loop shape).
// out = relu( dinv[d]*( h[d]*dinv[d] + sum_s h[s]*dinv[s] ) + bias )
__global__ __launch_bounds__(256) void k_gather_bf16(
        const unsigned short* __restrict__ h,   // bf16 [N][256]
        const int* __restrict__ srcs, const int* __restrict__ starts,
        const float* __restrict__ dinv, const float* __restrict__ bias,
        unsigned short* __restrict__ out, int N, int H) {
    int d = blockIdx.x * 4 + (threadIdx.x >> 6);
    if (d >= N) return;
    int lane = threadIdx.x & 63;
    int f0 = lane * 4;
    float dd = dinv[d];
    int e0 = starts[d], e1 = starts[d + 1];
    int cnt = e1 - e0;
    int cpre = cnt < 64 ? cnt : 64;

    float acc[4];
    {   // self-loop
        uint2 v = *(const uint2*)&h[((long long)d << 8) + f0];
        acc[0] = acc[1] = acc[2] = acc[3] = 0.0f;
        fma4(v, dd, acc);
    }
    int sv = 0; float nv = 0.0f;
    if (lane < cpre) { sv = srcs[e0 + lane]; nv = dinv[sv]; }
    int j = 0;
    for (; j + 1 < cpre; j += 2) {
        int s0 = __shfl(sv, j), s1 = __shfl(sv, j + 1);
        float n0 = __shfl(nv, j), n1 = __shfl(nv, j + 1);
        uint2 v0 = *(const uint2*)&h[((long long)s0 << 8) + f0];
        uint2 v1 = *(const uint2*)&h[((long long)s1 << 8) + f0];
        fma4(v0, n0, acc);
        fma4(v1, n1, acc);
    }
    if (j < cpre) {
        int s0 = __shfl(sv, j);
        float n0 = __shfl(nv, j);
        uint2 v0 = *(const uint2*)&h[((long long)s0 << 8) + f0];
        fma4(v0, n0, acc);
    }
    for (int e = e0 + 64; e < e1; e++) {           // rare: degree > 64
        int s0 = srcs[e];
        float n0 = dinv[s0];
        uint2 v0 = *(const uint2*)&h[((long long)s0 << 8) + f0];
        fma4(v0, n0, acc);
    }

    unsigned short o[4];
#pragma unroll
    for (int t = 0; t < 4; t++) {
        int f = f0 + t;
        float bb = (f < H) ? bias[f] : 0.0f;
        float v = fmaxf(acc[t] * dd + bb, 0.0f);   // relu; pad cols stay 0
        o[t] = f2bf(v);
    }
    unsigned o01 = (unsigned)o[0] | ((unsigned)o[1] << 16);
    unsigned o23 = (unsigned)o[2] | ((unsigned)o[3] << 16);
    *(uint2*)&out[((long long)d << 8) + f0] = make_uint2(o01, o23);
}

// ---------------- layer-4: gather + fused log_softmax ----------------------
__global__ __launch_bounds__(256) void k_gather_lsm(
        const unsigned short* __restrict__ h,   // bf16 [N][256]
        const int* __restrict__ srcs, const int* __restrict__ starts,
        const float* __restrict__ dinv, const float* __restrict__ bias,
        float* __restrict__ out, int N, int H) {
    int d = blockIdx.x * 4 + (threadIdx.x >> 6);
    if (d >= N) return;
    int lane = threadIdx.x & 63;
    int f0 = lane * 4;
    float dd = dinv[d];
    int e0 = starts[d], e1 = starts[d + 1];
    int cnt = e1 - e0;
    int cpre = cnt < 64 ? cnt : 64;

    float acc[4];
    {
        uint2 v = *(const uint2*)&h[((long long)d << 8) + f0];
        acc[0] = acc[1] = acc[2] = acc[3] = 0.0f;
        fma4(v, dd, acc);
    }
    int sv = 0; float nv = 0.0f;
    if (lane < cpre) { sv = srcs[e0 + lane]; nv = dinv[sv]; }
    int j = 0;
    for (; j + 1 < cpre; j += 2) {
        int s0 = __shfl(sv, j), s1 = __shfl(sv, j + 1);
        float n0 = __shfl(nv, j), n1 = __shfl(nv, j + 1);
        uint2 v0 = *(const uint2*)&h[((long long)s0 << 8) + f0];
        uint2 v1 = *(const uint2*)&h[((long long)s1 << 8) + f0];
        fma4(v0, n0, acc);
        fma4(v1, n1, acc);
    }
    if (j < cpre) {
        int s0 = __shfl(sv, j);
        float n0 = __shfl(nv, j);
        uint2 v0 = *(const uint2*)&h[((long long)s0 << 8) + f0];
        fma4(v0, n0, acc);
    }
    for (int e = e0 + 64; e < e1; e++) {
        int s0 = srcs[e];
        float n0 = dinv[s0];
        uint2 v0 = *(const uint2*)&h[((long long)s0 << 8) + f0];
        fma4(v0, n0, acc);
    }

    float v[4];
    float m = -INFINITY;
#pragma unroll
    for (int t = 0; t < 4; t++) {
        int f = f0 + t;
        float bb = (f < H) ? bias[f] : 0.0f;
        v[t] = acc[t] * dd + bb;
        if (f < H) m = fmaxf(m, v[t]);
    }
#pragma unroll
    for (int off = 32; off > 0; off >>= 1) m = fmaxf(m, __shfl_xor(m, off));
    float s = 0.0f;
#pragma unroll
    for (int t = 0; t < 4; t++) {
        int f = f0 + t;
        if (f < H) s += __expf(v[t] - m);
    }
#pragma unroll
    for (int off = 32; off > 0; off >>= 1) s += __shfl_xor(s, off);
    float lse = m + logf(s);
#pragma unroll
    for (int t = 0; t < 4; t++) {
        int f = f0 + t;
        if (f < H) out[(long long)d * H + f] = v[t] - lse;
    }
}

// ---------------------------------------------------------------------------
extern "C" void kernel_launch(void* const* d_in, const int* in_sizes, int n_in,
                              void* d_out, int out_size, void* d_ws, size_t ws_size,
                              hipStream_t stream) {
    const float* x    = (const float*)d_in[0];
    const void*  eidx = d_in[1];
    const float* W[4] = {(const float*)d_in[2], (const float*)d_in[4],
                         (const float*)d_in[6], (const float*)d_in[8]};
    const float* b[4] = {(const float*)d_in[3], (const float*)d_in[5],
                         (const float*)d_in[7], (const float*)d_in[9]};

    const int H   = in_sizes[3];          // 246
    const int E   = in_sizes[1] / 2;      // 320000
    const int FIN = in_sizes[2] / H;      // 256
    const int N   = in_sizes[0] / FIN;    // 50000

    auto align = [](size_t v) { return (v + 255) / 256 * 256; };
    char* ws = (char*)d_ws;
    size_t off = 0;
    int* flag = (int*)(ws + off);             off += 256;
    float* dinv = (float*)(ws + off);         off += align((size_t)N * 4);
    int* counts = (int*)(ws + off);           off += align((size_t)N * 4);
    int* starts = (int*)(ws + off);           off += align((size_t)(N + 1) * 4);
    int* srcs = (int*)(ws + off);             off += align((size_t)E * 4);
    unsigned short* Wt[4];
    for (int l = 0; l < 4; l++) {
        Wt[l] = (unsigned short*)(ws + off);  off += 256 * 256 * 2;
    }
    size_t actB = align((size_t)N * 256 * 2);
    unsigned short* A0 = (unsigned short*)(ws + off);  off += actB;
    unsigned short* A1 = (unsigned short*)(ws + off);  off += actB;
    unsigned short* Cb = (unsigned short*)(ws + off);  off += actB;

    int nb = (N + 255) / 256, eb = (E + 255) / 256;

    // --- edge dtype detection ---
    k_flag_init<<<1, 64, 0, stream>>>(flag);
    k_flag_check<<<512, 256, 0, stream>>>((const long long*)eidx, E, (long long)N, flag);

    // --- CSR build ---
    k_zero_i32<<<nb, 256, 0, stream>>>(counts, N);
    k_count<<<eb, 256, 0, stream>>>(eidx, flag, counts, E);
    k_dinv<<<nb, 256, 0, stream>>>(counts, dinv, N);
    k_scan<<<1, 1024, 0, stream>>>(counts, starts, N);
    k_copy_i32<<<nb, 256, 0, stream>>>(starts, counts, N);
    k_fill<<<eb, 256, 0, stream>>>(eidx, flag, counts, srcs, E);

    // --- weight + input conversion ---
    k_cvt_w<<<256, 256, 0, stream>>>(W[0], Wt[0], FIN, H);
    for (int l = 1; l < 4; l++)
        k_cvt_w<<<256, 256, 0, stream>>>(W[l], Wt[l], H, H);
    k_cvt_x<<<1024, 256, 0, stream>>>(x, A0, (long long)N * FIN / 4);

    dim3 ggrid(2, (N + 127) / 128);
    int gb = (N + 3) / 4;

    // --- layer 1 ---
    k_gemm_mfma<<<ggrid, 256, 0, stream>>>(A0, Wt[0], Cb, N);
    k_gather_bf16<<<gb, 256, 0, stream>>>(Cb, srcs, starts, dinv, b[0], A1, N, H);
    // --- layer 2 ---
    k_gemm_mfma<<<ggrid, 256, 0, stream>>>(A1, Wt[1], Cb, N);
    k_gather_bf16<<<gb, 256, 0, stream>>>(Cb, srcs, starts, dinv, b[1], A0, N, H);
    // --- layer 3 ---
    k_gemm_mfma<<<ggrid, 256, 0, stream>>>(A0, Wt[2], Cb, N);
    k_gather_bf16<<<gb, 256, 0, stream>>>(Cb, srcs, starts, dinv, b[2], A1, N, H);
    // --- layer 4 (fused log_softmax) ---
    k_gemm_mfma<<<ggrid, 256, 0, stream>>>(A1, Wt[3], Cb, N);
    k_gather_lsm<<<gb, 256, 0, stream>>>(Cb, srcs, starts, dinv, b[3],
                                         (float*)d_out, N, H);
}